// Round 4
// baseline (214.512 us; speedup 1.0000x reference)
//
#include <hip/hip_runtime.h>
#include <hip/hip_bf16.h>
#include <math.h>

// out[b, :] = z[b, :] @ W[c_b*12288 : (c_b+1)*12288, :]^T + bias[c_b block]
//   z: (512,128) f32, W: (196608,128) f32, bias: (196608,), out: (512,12288) f32
//   c_b = mod(floor(|np.sum_f32_pairwise(z[b])| * 1000), 16)   (numpy-exact order)
//
// R8: R7 confirmed spill-free z-in-LDS (WRITE back to 24576KB exactly) but
// time stuck at ~63us: LDS-ISSUE-BOUND. Each vf16 z load = 4x ds_read_b128;
// 12 reads/k-step x 1536/pass x 12 waves/CU ~ 18.4K b128/CU ~ 61-92us of
// LDS pipe at 8-12cyc/instr -- matches measurement; broadcasts deliver only
// 16B/instr. Fix: 2 columns per thread (TJ=128, cols j and j+128), same 12
// ds_reads now feed 96 FMA-floats/k-step -> total ds_read count halves
// (4.7M -> 2.36M). W traffic unchanged (each row still read once by one
// thread). W ring 4-deep per row; launch_bounds(128,2) caps VGPR at 256.

#define N_LINEARS 16
#define ZD 128
#define BATCH 512
#define BLOCK_OUT 12288
#define STILE 48                  // one W pass for n<=48 (Binom mean 32, sd 5.5)
#define SLOTS 64
#define ZROWS (ZD + 1)
#define TJ 128                    // threads/block; each thread owns 2 columns

typedef float vf16 __attribute__((ext_vector_type(16)));
typedef vf16 vf16u __attribute__((aligned(16)));   // 16B-aligned vector loads

// ws layout: [0,64) counts | [64, 64+32768) lists | [36864, +2048) bp | zgT @65536
#define LISTS_OFF 16
#define BP_OFF (36864 / 4)
#define ZG_OFF_BYTES 65536

// ---------------- Kernel A1: hash (1 block, LDS atomics) ----------------
__global__ __launch_bounds__(512) void hash_kernel(
    const float* __restrict__ z, int* __restrict__ counts,
    int* __restrict__ lists, int* __restrict__ bp) {
  __shared__ int cnt[N_LINEARS];
  const int b = threadIdx.x;
  if (b < N_LINEARS) cnt[b] = 0;
  __syncthreads();

  // numpy pairwise_sum (n=128 <= PW_BLOCKSIZE): 8 stride-8 accumulators,
  // combined ((r0+r1)+(r2+r3))+((r4+r5)+(r6+r7)). float4 loads keep the
  // exact same per-accumulator add order; 32 loads instead of 128.
  const float4* zr4 = (const float4*)(z + b * ZD);
  const float4 pa = zr4[0], pb = zr4[1];
  float r0 = pa.x, r1 = pa.y, r2 = pa.z, r3 = pa.w;
  float r4 = pb.x, r5 = pb.y, r6 = pb.z, r7 = pb.w;
  #pragma unroll
  for (int i = 2; i < ZD / 4; i += 2) {
    const float4 a = zr4[i], d = zr4[i + 1];
    r0 += a.x; r1 += a.y; r2 += a.z; r3 += a.w;
    r4 += d.x; r5 += d.y; r6 += d.z; r7 += d.w;
  }
  float res = ((r0 + r1) + (r2 + r3)) + ((r4 + r5) + (r6 + r7));
  float v = fabsf(res) * 1000.0f;
  int cb = ((int)floorf(v)) & (N_LINEARS - 1);

  int pos = atomicAdd(&cnt[cb], 1);          // LDS atomic: fast, no XCD traffic
  lists[(cb << 9) + pos] = b;
  bp[b] = cb | (pos << 4);

  __syncthreads();
  if (b < N_LINEARS) counts[b] = cnt[b];
}

// ---------------- Kernel A2: z scatter into bucket-grouped k-major zgT ----
// zgT[c][k][slot]; 512 blocks (one per sample) x 128 threads (one per k).
__global__ __launch_bounds__(128) void gather_kernel(
    const float* __restrict__ z, const int* __restrict__ bp,
    float* __restrict__ zgT) {
  const int b = blockIdx.x;
  const int k = threadIdx.x;
  const int v = bp[b];
  const int cb = v & 15;
  const int pos = v >> 4;
  if (pos < SLOTS)
    zgT[(size_t)cb * (ZROWS * SLOTS) + (size_t)k * SLOTS + pos] = z[b * ZD + k];
}

// ---------------- Kernel B: grouped GEMM ----------------
// grid (48 j-tiles, 16 buckets) x 128 thr; thread owns columns j0=bx*256+t
// and j1=j0+128, 48 sample accs per column (2x3 vf16). z tile in LDS, read
// by DIRECT zsh[] indexing (ds_read_b128 broadcast, lgkmcnt); each z read
// feeds BOTH columns. W: two rows, each a 4-deep float4 ring (sole vmcnt
// user, never drained).

#define ZLOAD(N0, N1, N2, K1)                                        \
  { const int zo_ = (K1) * SLOTS + s0;                               \
    N0 = *(const vf16u*)&zsh[zo_];                                   \
    N1 = *(const vf16u*)&zsh[zo_ + 16];                              \
    N2 = *(const vf16u*)&zsh[zo_ + 32]; }

#define ZFMA2(C0, C1, C2, WKA, WKB)                                  \
  { const float wka_ = (WKA), wkb_ = (WKB);                          \
    vf16 wva_, wvb_;                                                 \
    _Pragma("unroll") for (int e = 0; e < 16; ++e) wva_[e] = wka_;   \
    _Pragma("unroll") for (int e = 0; e < 16; ++e) wvb_[e] = wkb_;   \
    accA0 += C0 * wva_; accA1 += C1 * wva_; accA2 += C2 * wva_;      \
    accB0 += C0 * wvb_; accB1 += C1 * wvb_; accB2 += C2 * wvb_; }

#define STEP(C0, C1, C2, N0, N1, N2, K1, WKA, WKB)                   \
  ZLOAD(N0, N1, N2, K1) ZFMA2(C0, C1, C2, WKA, WKB)

__global__ __launch_bounds__(TJ, 2) void gen_main_kernel(
    const float* __restrict__ W, const float* __restrict__ bias,
    float* __restrict__ out, const int* __restrict__ counts,
    const int* __restrict__ lists, const float* __restrict__ zgT) {
  // 128 rows x 64 slots, +96 floats of slack so pass-2 (s0=48) reads of
  // slots 48..95 stay in-bounds (values are garbage, masked by t<m).
  __shared__ float zsh[ZD * SLOTS + 96];
  const int c = blockIdx.y;
  const int t = threadIdx.x;
  const int j0 = blockIdx.x * (2 * TJ) + t;    // column A
  const int j1 = j0 + TJ;                      // column B
  int n = counts[c];
  n = n > SLOTS ? SLOTS : n;
  if (n == 0) return;                    // uniform per block: safe before barrier

  {  // stage rows 0..127 (8192 floats = 2048 quads = 16*128, linear, coalesced)
    const float4* zg4 = (const float4*)(zgT + (size_t)c * (ZROWS * SLOTS));
    float4* ls4 = (float4*)zsh;
    #pragma unroll
    for (int i = 0; i < 16; ++i) {
      const int idx = t + i * TJ;
      ls4[idx] = zg4[idx];
    }
  }
  __syncthreads();

  const size_t row0 = (size_t)c * BLOCK_OUT + (size_t)j0;
  const size_t row1 = row0 + TJ;
  const float4* __restrict__ Wv0 = (const float4*)(W + row0 * (size_t)ZD);
  const float4* __restrict__ Wv1 = (const float4*)(W + row1 * (size_t)ZD);
  const float bj0 = bias[row0];
  const float bj1 = bias[row1];
  const int* __restrict__ lst = lists + (c << 9);

  for (int s0 = 0; s0 < n; s0 += STILE) {
    const int m = n - s0;
    vf16 accA0, accA1, accA2, accB0, accB1, accB2;
    #pragma unroll
    for (int e = 0; e < 16; ++e) {
      accA0[e] = bj0; accA1[e] = bj0; accA2[e] = bj0;
      accB0[e] = bj1; accB1[e] = bj1; accB2[e] = bj1;
    }

    vf16 zA0, zA1, zA2, zB0, zB1, zB2;
    ZLOAD(zA0, zA1, zA2, 0)
    float4 wa0 = Wv0[0], wa1 = Wv0[1], wa2 = Wv0[2], wa3 = Wv0[3];
    float4 wb0 = Wv1[0], wb1 = Wv1[1], wb2 = Wv1[2], wb3 = Wv1[3];

    #pragma unroll 2
    for (int kc = 0; kc < ZD / 4; ++kc) {
      const int k0 = kc * 4;
      STEP(zA0, zA1, zA2, zB0, zB1, zB2, k0 + 1, wa0.x, wb0.x)
      STEP(zB0, zB1, zB2, zA0, zA1, zA2, k0 + 2, wa0.y, wb0.y)
      STEP(zA0, zA1, zA2, zB0, zB1, zB2, k0 + 3, wa0.z, wb0.z)
      STEP(zB0, zB1, zB2, zA0, zA1, zA2, k0 + 4, wa0.w, wb0.w) // kc=31: slack row
      wa0 = wa1; wa1 = wa2; wa2 = wa3;
      wb0 = wb1; wb1 = wb2; wb2 = wb3;
      const int wi = kc + 4 > 31 ? 31 : kc + 4;
      wa3 = Wv0[wi];                     // ring depth 4: auto-wait ~vmcnt(6)
      wb3 = Wv1[wi];
    }

    #pragma unroll
    for (int v = 0; v < 16; ++v)
      if (v < m) {
        const size_t ob = (size_t)lst[s0 + v] * BLOCK_OUT;
        out[ob + j0] = accA0[v]; out[ob + j1] = accB0[v];
      }
    #pragma unroll
    for (int v = 0; v < 16; ++v)
      if (16 + v < m) {
        const size_t ob = (size_t)lst[s0 + 16 + v] * BLOCK_OUT;
        out[ob + j0] = accA1[v]; out[ob + j1] = accB1[v];
      }
    #pragma unroll
    for (int v = 0; v < 16; ++v)
      if (32 + v < m) {
        const size_t ob = (size_t)lst[s0 + 32 + v] * BLOCK_OUT;
        out[ob + j0] = accA2[v]; out[ob + j1] = accB2[v];
      }
  }
}

extern "C" void kernel_launch(void* const* d_in, const int* in_sizes, int n_in,
                              void* d_out, int out_size, void* d_ws, size_t ws_size,
                              hipStream_t stream) {
  const float* z    = (const float*)d_in[0];   // 512*128
  const float* W    = (const float*)d_in[1];   // 196608*128
  const float* bias = (const float*)d_in[2];   // 196608
  float* out = (float*)d_out;                  // 512*12288

  int*   counts = (int*)d_ws;
  int*   lists  = (int*)d_ws + LISTS_OFF;
  int*   bp     = (int*)d_ws + BP_OFF;
  float* zgT    = (float*)((char*)d_ws + ZG_OFF_BYTES); // 16*129*64 floats

  hipLaunchKernelGGL(hash_kernel, dim3(1), dim3(BATCH), 0, stream,
                     z, counts, lists, bp);
  hipLaunchKernelGGL(gather_kernel, dim3(BATCH), dim3(ZD), 0, stream,
                     z, bp, zgT);

  dim3 grid(BLOCK_OUT / (2 * TJ), N_LINEARS);  // (48, 16)
  hipLaunchKernelGGL(gen_main_kernel, grid, dim3(TJ), 0, stream,
                     W, bias, out, counts, lists, zgT);
}